// Round 8
// baseline (53.688 us; speedup 1.0000x reference)
//
#include <hip/hip_runtime.h>
#include <hip/hip_bf16.h>

typedef __attribute__((ext_vector_type(8))) short s16x8;
typedef __attribute__((ext_vector_type(4))) short s16x4;
typedef __attribute__((ext_vector_type(4))) float fx4;

#define DEVINL __device__ __forceinline__

constexpr int EMBED = 768;
constexpr int HD    = 64;
constexpr int NB    = 16;
constexpr int LEN   = 1024;
constexpr int M_TOT = NB * LEN;   // 16384
constexpr int KVQ   = LEN / 4;    // 256 kv per group in fused attn
constexpr int WELEM = HD * EMBED; // 49152

// fp32 -> bf16 RNE via v_cvt_pk_bf16_f32 (2 elems/inst).
DEVINL unsigned pk2(float lo, float hi) {
  __hip_bfloat162 h = __float22bfloat162_rn(float2{lo, hi});
  union { __hip_bfloat162 h; unsigned u; } c; c.h = h;
  return c.u;
}
DEVINL s16x8 cvt8(fx4 a, fx4 b) {
  union { unsigned u[4]; s16x8 v; } r;
  r.u[0] = pk2(a[0], a[1]); r.u[1] = pk2(a[2], a[3]);
  r.u[2] = pk2(b[0], b[1]); r.u[3] = pk2(b[2], b[3]);
  return r.v;
}
DEVINL s16x4 cvt4(float a0, float a1, float a2, float a3) {
  union { unsigned u[2]; s16x4 v; } r;
  r.u[0] = pk2(a0, a1); r.u[1] = pk2(a2, a3);
  return r.v;
}
DEVINL s16x4 cvt4v(fx4 a) { return cvt4(a[0], a[1], a[2], a[3]); }

DEVINL fx4 mfma16(s16x8 a, s16x8 b, fx4 c) {
  return __builtin_amdgcn_mfma_f32_16x16x32_bf16(a, b, c, 0, 0, 0);
}

// ---------------------------------------------------------------------------
// One-shot: convert Wq|Wk|Wv (each 64x768 fp32) to bf16, packed [3][49152].
// ---------------------------------------------------------------------------
__global__ __launch_bounds__(256) void convert_w_kernel(
    const float* __restrict__ a, const float* __restrict__ b,
    const float* __restrict__ c, short* __restrict__ out)
{
  const int gid = blockIdx.x * 256 + threadIdx.x;   // 18432 threads, 8 elem each
  const int seg = gid / (WELEM / 8);
  const int off = (gid % (WELEM / 8)) * 8;
  const float* src = (seg == 0) ? a : (seg == 1) ? b : c;
  fx4 v0 = *reinterpret_cast<const fx4*>(src + off);
  fx4 v1 = *reinterpret_cast<const fx4*>(src + off + 4);
  *reinterpret_cast<s16x8*>(out + (size_t)seg * WELEM + off) = cvt8(v0, v1);
}

// ---------------------------------------------------------------------------
// Projection design (round 8): pay memory latency ONCE per block.
//   - 512 threads = 8 waves, M=32 rows/block, grid 512, bounds (512,1)
//     -> VGPR cap 256, no spill, no forced-64 straitjacket.
//   - W bf16 -> 24 register fragments per wave (L2-resident, loaded first).
//   - X staged in ONE burst: 12 fx4/thread, chunked 6-deep for ILP, cvt_pk,
//     ds_write_b64; ONE __syncthreads; then 24 MFMA steps with ZERO barriers
//     and ZERO global loads (waves independent -> no vmcnt(0) drains).
//   - LDS [32][792] shorts: stride 396 dwords -> 2-way bank aliasing (free).
// ---------------------------------------------------------------------------
constexpr int XPITCH = 792;  // shorts per row (768 + 24 pad)

template <typename STAGEF>
DEVINL void stage_x(const float* xrow, int sc, short* dst) {
  // staging body shared by both kernels via lambda-free inline
}

__global__ __launch_bounds__(512, 1) void proj_q_kernel(
    const float* __restrict__ X, const short* __restrict__ Wb,
    const float* __restrict__ bias, short* __restrict__ Y)
{
  __shared__ short Xls[32][XPITCH];
  const int t = threadIdx.x, lane = t & 63, wv = t >> 6;
  const int c = wv >> 1, ms = wv & 1;
  const int fr = lane & 15, fg = lane >> 4;
  const int m0 = blockIdx.x * 32;

  // ---- W fragments -> registers (24 x 16B, L2-resident) ----
  const short* wbase = Wb + (size_t)(c * 16 + fr) * EMBED + fg * 8;
  s16x8 wf[24];
#pragma unroll
  for (int s = 0; s < 24; ++s)
    wf[s] = *reinterpret_cast<const s16x8*>(wbase + s * 32);

  // ---- single-burst X staging ----
  // thread covers row srow; 12 fx4 at col (t&15)*4 + i*64 (16 thr/row,
  // consecutive threads contiguous 256B per i -> coalesced)
  const int srow = t >> 4, sc = (t & 15) * 4;
  const float* xrow = X + (size_t)(m0 + srow) * EMBED + sc;
#pragma unroll
  for (int h = 0; h < 2; ++h) {
    fx4 f[6];
#pragma unroll
    for (int i = 0; i < 6; ++i)
      f[i] = *reinterpret_cast<const fx4*>(xrow + (h * 6 + i) * 64);
#pragma unroll
    for (int i = 0; i < 6; ++i)
      *reinterpret_cast<s16x4*>(&Xls[srow][(h * 6 + i) * 64 + sc]) = cvt4v(f[i]);
  }
  __syncthreads();  // the ONLY barrier

  // ---- 24 barrier-free MFMA steps ----
  fx4 acc = fx4{0.f, 0.f, 0.f, 0.f};
#pragma unroll
  for (int s = 0; s < 24; ++s) {
    s16x8 xa = *reinterpret_cast<const s16x8*>(&Xls[ms * 16 + fr][s * 32 + fg * 8]);
    acc = mfma16(wf[s], xa, acc);  // D[d][m]: d=c*16+fg*4+r, m-col=fr
  }

  // ---- epilogue ----
  fx4 b4 = *reinterpret_cast<const fx4*>(bias + c * 16 + fg * 4);
  *reinterpret_cast<s16x4*>(Y + (size_t)(m0 + ms * 16 + fr) * HD + c * 16 + fg * 4) =
      cvt4(acc[0] + b4[0], acc[1] + b4[1], acc[2] + b4[2], acc[3] + b4[3]);
}

__global__ __launch_bounds__(512, 1) void proj_kv_kernel(
    const float* __restrict__ X,
    const short* __restrict__ Wkb, const float* __restrict__ bk,
    const short* __restrict__ Wvb, const float* __restrict__ bv,
    short* __restrict__ Kout, short* __restrict__ VT)
{
  __shared__ short Xls[32][XPITCH];
  const int t = threadIdx.x, lane = t & 63, wv = t >> 6;
  const int c = wv >> 1, mat = wv & 1;   // mat: 0 -> K, 1 -> V
  const int fr = lane & 15, fg = lane >> 4;
  const int m0 = blockIdx.x * 32;

  const short* wbase = (mat ? Wvb : Wkb) + (size_t)(c * 16 + fr) * EMBED + fg * 8;
  s16x8 wf[24];
#pragma unroll
  for (int s = 0; s < 24; ++s)
    wf[s] = *reinterpret_cast<const s16x8*>(wbase + s * 32);

  const int srow = t >> 4, sc = (t & 15) * 4;
  const float* xrow = X + (size_t)(m0 + srow) * EMBED + sc;
#pragma unroll
  for (int h = 0; h < 2; ++h) {
    fx4 f[6];
#pragma unroll
    for (int i = 0; i < 6; ++i)
      f[i] = *reinterpret_cast<const fx4*>(xrow + (h * 6 + i) * 64);
#pragma unroll
    for (int i = 0; i < 6; ++i)
      *reinterpret_cast<s16x4*>(&Xls[srow][(h * 6 + i) * 64 + sc]) = cvt4v(f[i]);
  }
  __syncthreads();  // the ONLY barrier

  fx4 acc[2];
  acc[0] = fx4{0.f, 0.f, 0.f, 0.f};
  acc[1] = fx4{0.f, 0.f, 0.f, 0.f};
#pragma unroll
  for (int s = 0; s < 24; ++s) {
    s16x8 xa0 = *reinterpret_cast<const s16x8*>(&Xls[fr][s * 32 + fg * 8]);
    s16x8 xa1 = *reinterpret_cast<const s16x8*>(&Xls[16 + fr][s * 32 + fg * 8]);
    acc[0] = mfma16(wf[s], xa0, acc[0]);
    acc[1] = mfma16(wf[s], xa1, acc[1]);
  }

  if (mat == 0) {
    // K: row-major bf16 [m][d]
    fx4 b4 = *reinterpret_cast<const fx4*>(bk + c * 16 + fg * 4);
#pragma unroll
    for (int ms = 0; ms < 2; ++ms)
      *reinterpret_cast<s16x4*>(Kout + (size_t)(m0 + ms * 16 + fr) * HD + c * 16 + fg * 4) =
          cvt4(acc[ms][0] + b4[0], acc[ms][1] + b4[1],
               acc[ms][2] + b4[2], acc[ms][3] + b4[3]);
  } else {
    // V^T: [b][d][kv]; lanes fr=0..15 contiguous kv -> 32B segments
    fx4 b4 = *reinterpret_cast<const fx4*>(bv + c * 16 + fg * 4);
    const int bidx = m0 >> 10;              // 32 | 1024: no batch straddle
    const int kvbase = (m0 & 1023) + fr;
#pragma unroll
    for (int ms = 0; ms < 2; ++ms)
#pragma unroll
      for (int r = 0; r < 4; ++r) {
        const int d = c * 16 + fg * 4 + r;
        VT[((size_t)(bidx * HD + d)) * LEN + kvbase + ms * 16] =
            (short)pk2(acc[ms][r] + b4[r], 0.f);
      }
  }
}

// ---------------------------------------------------------------------------
// Fused flash attention (unchanged from round 5-7; ~3 us). 1024 threads =
// 16 waves = 4 KV-groups x 4 q-waves; K/V LDS-staged per group; lane-local
// softmax; partial combine through LDS overlay.
// ---------------------------------------------------------------------------
__global__ __launch_bounds__(1024, 4) void attn_kernel(
    const short* __restrict__ Q, const short* __restrict__ K,
    const short* __restrict__ VT, float* __restrict__ Out)
{
  __shared__ __align__(16) char smem[110592];
  short (*Kls)[64][72]  = reinterpret_cast<short(*)[64][72]>(smem);
  short (*Vls)[64][72]  = reinterpret_cast<short(*)[64][72]>(smem + 36864);
  short (*Plds)[16][72] = reinterpret_cast<short(*)[16][72]>(smem + 73728);
  float (*HL)[64][68]   = reinterpret_cast<float(*)[64][68]>(smem);
  float2 (*ML)[64]      = reinterpret_cast<float2(*)[64]>(smem + 69632);

  const int t = threadIdx.x, lane = t & 63, w = t >> 6;
  const int g = w >> 2, wl = w & 3;
  const int fr = lane & 15, fg = lane >> 4;
  const int xcd = blockIdx.x & 7;
  const int idx = blockIdx.x >> 3;        // 0..31
  const int b   = xcd + ((idx & 1) << 3);
  const int q0  = (idx >> 1) * 64;
  const int qrow = q0 + wl * 16;

  const short* Qb  = Q  + (size_t)b * LEN * HD;
  const short* Kb  = K  + ((size_t)b * LEN + g * KVQ) * HD;
  const short* VTb = VT + (size_t)b * HD * LEN + g * KVQ;

  s16x8 qa0 = *reinterpret_cast<const s16x8*>(Qb + (size_t)(qrow + fr) * HD + fg * 8);
  s16x8 qa1 = *reinterpret_cast<const s16x8*>(Qb + (size_t)(qrow + fr) * HD + 32 + fg * 8);

  fx4 hacc[4];
#pragma unroll
  for (int c = 0; c < 4; ++c) hacc[c] = fx4{0.f, 0.f, 0.f, 0.f};
  float mrun = -1e30f, lsum = 0.f;
  const float SC = 0.125f * 1.44269504088896340736f;  // 1/sqrt(64) * log2(e)

  const int u = t & 255;
  const int srow = u >> 2;          // 0..63
  const int sch  = (u & 3) * 16;    // short col offset: 0,16,32,48 (32B/lane)

  s16x8 pk0 = *reinterpret_cast<const s16x8*>(Kb + (size_t)srow * HD + sch);
  s16x8 pk1 = *reinterpret_cast<const s16x8*>(Kb + (size_t)srow * HD + sch + 8);
  s16x8 pv0 = *reinterpret_cast<const s16x8*>(VTb + (size_t)srow * LEN + sch);
  s16x8 pv1 = *reinterpret_cast<const s16x8*>(VTb + (size_t)srow * LEN + sch + 8);
  *reinterpret_cast<s16x8*>(&Kls[g][srow][sch])     = pk0;
  *reinterpret_cast<s16x8*>(&Kls[g][srow][sch + 8]) = pk1;
  *reinterpret_cast<s16x8*>(&Vls[g][srow][sch])     = pv0;
  *reinterpret_cast<s16x8*>(&Vls[g][srow][sch + 8]) = pv1;
  __syncthreads();

#pragma unroll
  for (int it = 0; it < KVQ / 64; ++it) {
    if (it + 1 < KVQ / 64) {  // issue next tile's loads before compute
      const int nk = (it + 1) * 64;
      pk0 = *reinterpret_cast<const s16x8*>(Kb + (size_t)(nk + srow) * HD + sch);
      pk1 = *reinterpret_cast<const s16x8*>(Kb + (size_t)(nk + srow) * HD + sch + 8);
      pv0 = *reinterpret_cast<const s16x8*>(VTb + (size_t)srow * LEN + nk + sch);
      pv1 = *reinterpret_cast<const s16x8*>(VTb + (size_t)srow * LEN + nk + sch + 8);
    }
    fx4 sacc[4];
#pragma unroll
    for (int s = 0; s < 4; ++s) {
      s16x8 kf0 = *reinterpret_cast<const s16x8*>(&Kls[g][s * 16 + fr][fg * 8]);
      s16x8 kf1 = *reinterpret_cast<const s16x8*>(&Kls[g][s * 16 + fr][32 + fg * 8]);
      fx4 z = fx4{0.f, 0.f, 0.f, 0.f};
      z = mfma16(kf0, qa0, z);
      sacc[s] = mfma16(kf1, qa1, z);
    }
    float xs[4][4];
    float xm = -1e30f;
#pragma unroll
    for (int s = 0; s < 4; ++s)
#pragma unroll
      for (int r = 0; r < 4; ++r) {
        xs[s][r] = sacc[s][r] * SC;
        xm = fmaxf(xm, xs[s][r]);
      }
    xm = fmaxf(xm, __shfl_xor(xm, 16, 64));
    xm = fmaxf(xm, __shfl_xor(xm, 32, 64));
    const float mn = fmaxf(mrun, xm);
    const float corr = __builtin_amdgcn_exp2f(mrun - mn);
    mrun = mn;
    float ps = 0.f;
#pragma unroll
    for (int s = 0; s < 4; ++s) {
      float p[4];
#pragma unroll
      for (int r = 0; r < 4; ++r) {
        p[r] = __builtin_amdgcn_exp2f(xs[s][r] - mn);
        ps += p[r];
      }
      *reinterpret_cast<s16x4*>(&Plds[w][fr][s * 16 + fg * 4]) =
          cvt4(p[0], p[1], p[2], p[3]);
    }
    ps += __shfl_xor(ps, 16, 64);
    ps += __shfl_xor(ps, 32, 64);
    lsum = lsum * corr + ps;
    __builtin_amdgcn_wave_barrier();
    s16x8 pa0 = *reinterpret_cast<const s16x8*>(&Plds[w][fr][fg * 8]);
    s16x8 pa1 = *reinterpret_cast<const s16x8*>(&Plds[w][fr][32 + fg * 8]);
#pragma unroll
    for (int c = 0; c < 4; ++c) {
      s16x8 vf0 = *reinterpret_cast<const s16x8*>(&Vls[g][c * 16 + fr][fg * 8]);
      s16x8 vf1 = *reinterpret_cast<const s16x8*>(&Vls[g][c * 16 + fr][32 + fg * 8]);
      fx4 h = hacc[c];
#pragma unroll
      for (int r = 0; r < 4; ++r) h[r] *= corr;
      h = mfma16(vf0, pa0, h);
      hacc[c] = mfma16(vf1, pa1, h);
    }
    __syncthreads();  // all waves done reading tile it
    if (it + 1 < KVQ / 64) {
      *reinterpret_cast<s16x8*>(&Kls[g][srow][sch])     = pk0;
      *reinterpret_cast<s16x8*>(&Kls[g][srow][sch + 8]) = pk1;
      *reinterpret_cast<s16x8*>(&Vls[g][srow][sch])     = pv0;
      *reinterpret_cast<s16x8*>(&Vls[g][srow][sch + 8]) = pv1;
    }
    __syncthreads();  // tile it+1 visible
  }
#pragma unroll
  for (int c = 0; c < 4; ++c)
    *reinterpret_cast<fx4*>(&HL[g][wl * 16 + fr][c * 16 + fg * 4]) = hacc[c];
  if (fg == 0) ML[g][wl * 16 + fr] = make_float2(mrun, lsum);
  __syncthreads();
  const int row = t >> 4, d0 = (t & 15) * 4;
  const float2 s0 = ML[0][row], s1 = ML[1][row], s2 = ML[2][row], s3 = ML[3][row];
  const float mm = fmaxf(fmaxf(s0.x, s1.x), fmaxf(s2.x, s3.x));
  const float w0 = __builtin_amdgcn_exp2f(s0.x - mm);
  const float w1 = __builtin_amdgcn_exp2f(s1.x - mm);
  const float w2 = __builtin_amdgcn_exp2f(s2.x - mm);
  const float w3 = __builtin_amdgcn_exp2f(s3.x - mm);
  const float inv = 1.0f / (s0.y * w0 + s1.y * w1 + s2.y * w2 + s3.y * w3);
  fx4 h0 = *reinterpret_cast<const fx4*>(&HL[0][row][d0]);
  fx4 h1 = *reinterpret_cast<const fx4*>(&HL[1][row][d0]);
  fx4 h2 = *reinterpret_cast<const fx4*>(&HL[2][row][d0]);
  fx4 h3 = *reinterpret_cast<const fx4*>(&HL[3][row][d0]);
  fx4 o;
#pragma unroll
  for (int r = 0; r < 4; ++r)
    o[r] = (h0[r] * w0 + h1[r] * w1 + h2[r] * w2 + h3[r] * w3) * inv;
  *reinterpret_cast<fx4*>(Out + ((size_t)b * LEN + q0 + row) * HD + d0) = o;
}

extern "C" void kernel_launch(void* const* d_in, const int* in_sizes, int n_in,
                              void* d_out, int out_size, void* d_ws, size_t ws_size,
                              hipStream_t stream) {
  const float* dec = (const float*)d_in[0];
  const float* enc = (const float*)d_in[1];
  const float* Wq  = (const float*)d_in[2];
  const float* bq  = (const float*)d_in[3];
  const float* Wk  = (const float*)d_in[4];
  const float* bk  = (const float*)d_in[5];
  const float* Wv  = (const float*)d_in[6];
  const float* bv  = (const float*)d_in[7];
  float* out = (float*)d_out;

  short* qws  = (short*)d_ws;                        // [16384,64] bf16
  short* kws  = qws + (size_t)M_TOT * HD;            // [16384,64] bf16
  short* vtws = kws + (size_t)M_TOT * HD;            // [16,64,1024] bf16
  short* wbuf = vtws + (size_t)NB * HD * LEN;        // [3][49152] bf16 weights

  convert_w_kernel<<<(3 * WELEM / 8) / 256, 256, 0, stream>>>(Wq, Wk, Wv, wbuf);
  proj_q_kernel<<<M_TOT / 32, 512, 0, stream>>>(dec, wbuf, bq, qws);
  proj_kv_kernel<<<M_TOT / 32, 512, 0, stream>>>(enc, wbuf + WELEM, bk,
                                                 wbuf + 2 * (size_t)WELEM, bv,
                                                 kws, vtws);
  attn_kernel<<<NB * (LEN / 64), 1024, 0, stream>>>(qws, kws, vtws, out);
}